// Round 5
// baseline (189.962 us; speedup 1.0000x reference)
//
#include <hip/hip_runtime.h>

#define NCELLS 1024
#define LDIM   30
#define GDIM   10000
#define NBATCH 64
#define GPB    256     // genes per block
#define CH     64      // cell chunk staged in LDS per pass

typedef unsigned int  u32;

// grid = (NBATCH, ceil(G/GPB)), block = 256, one gene per thread.
// Batch-grouped: fused matrix M[g][l] = W[l,g] + A[b,g,l] built once per
// (batch, gene), reused for all ~16 cells of that batch -> A_emb (76.8 MB,
// the dominant traffic) is fetched from HBM exactly once.
// OUTPUTS ARE FLOAT32 (harness compares in bf16 domain but buffer is f32).
__global__ __launch_bounds__(256) void decoder_kernel(
    const float* __restrict__ z,      // [N,L]     f32
    const void*  __restrict__ cand1,  // [N]  bcov or sf (classified on device)
    const void*  __restrict__ cand2,  // [N]  the other one
    const float* __restrict__ W,      // [L,G]     f32
    const float* __restrict__ A,      // [NB,G,L]  f32
    const float* __restrict__ Bb,     // [NB,G]    f32
    const float* __restrict__ px,     // [G]       f32
    float* __restrict__ out)          // [N*G + G] f32
{
    const int b   = blockIdx.x;
    const int tid = threadIdx.x;
    const int gb  = blockIdx.y * GPB;
    const int g   = gb + tid;

    __shared__ __align__(16) float smem[GPB * LDIM];  // A-tile, later z/sf
    __shared__ int cells[NCELLS];
    __shared__ int cnt;

    // classify the two 1024-element inputs: int32 0..63 words all < 64u;
    // uniform-[0,1) f32 bit patterns are not. Uniform branch, L2-hot.
    bool c1_is_int = true;
    for (int i = 0; i < 64; i++)
        if (((const u32*)cand1)[i] >= 64u) { c1_is_int = false; break; }
    const int*   bcov = c1_is_int ? (const int*)cand1   : (const int*)cand2;
    const float* sf   = c1_is_int ? (const float*)cand2 : (const float*)cand1;

    if (tid == 0) cnt = 0;
    __syncthreads();
    for (int i = tid; i < NCELLS; i += 256)
        if (bcov[i] == b) cells[atomicAdd(&cnt, 1)] = i;

    // stage A tile [gb, gb+GPB) x [0,L): coalesced float4 loads.
    // abase = (b*G+gb)*30: gb%256==0 -> abase%4==0 -> 16B aligned.
    const size_t abase = ((size_t)b * GDIM + gb) * LDIM;
    const size_t atot  = (size_t)NBATCH * GDIM * LDIM;
    float4* smem4 = (float4*)smem;
    for (int i = tid; i < GPB * LDIM / 4; i += 256) {
        size_t idx = abase + (size_t)i * 4;
        float4 v = make_float4(0.f, 0.f, 0.f, 0.f);
        if (idx + 4 <= atot) v = *(const float4*)(A + idx);  // clamp: b=63 tail
        smem4[i] = v;
    }
    __syncthreads();   // covers cell scan + A staging

    float M[LDIM];
    float h3 = 0.f;
    const bool valid = (g < GDIM);
    if (valid) {
        #pragma unroll
        for (int l = 0; l < LDIM; l++) M[l] = smem[tid * LDIM + l];
        #pragma unroll
        for (int l = 0; l < LDIM; l++) M[l] += W[l * GDIM + g];  // coalesced, L2-hot
        h3 = Bb[(size_t)b * GDIM + g];
        // second output: inverse_dispersion = exp(px_r), f32 at offset N*G
        if (b == 0) out[(size_t)NCELLS * GDIM + g] = __expf(px[g]);
    }
    const int total = cnt;
    __syncthreads();   // A tile fully consumed before smem is reused for z

    float* z_sh  = smem;             // CH*LDIM floats
    float* sf_sh = smem + CH * LDIM; // CH floats
    for (int c0 = 0; c0 < total; c0 += CH) {
        const int nc = min(CH, total - c0);
        for (int i = tid; i < nc * LDIM; i += 256) {
            int cc = i / LDIM, l = i - cc * LDIM;
            z_sh[i] = z[(size_t)cells[c0 + cc] * LDIM + l];
        }
        for (int i = tid; i < nc; i += 256)
            sf_sh[i] = sf[cells[c0 + i]];
        __syncthreads();

        if (valid) {
            for (int cc = 0; cc < nc; cc++) {
                float acc = h3;
                #pragma unroll
                for (int l = 0; l < LDIM; l++)
                    acc = fmaf(M[l], z_sh[cc * LDIM + l], acc);  // broadcast read
                // stable softplus: max(x,0) + log1p(exp(-|x|))
                float sp = fmaxf(acc, 0.f) + log1pf(__expf(-fabsf(acc)));
                out[(size_t)cells[c0 + cc] * GDIM + g] = sp * sf_sh[cc];  // f32!
            }
        }
        __syncthreads();
    }
}

extern "C" void kernel_launch(void* const* d_in, const int* in_sizes, int n_in,
                              void* d_out, int out_size, void* d_ws, size_t ws_size,
                              hipStream_t stream) {
    // Bind inputs by element count (robust to ordering); the two 1024-element
    // inputs (bcov / size_factor) are disambiguated on device by content.
    const float* z  = nullptr;   // 30720
    const float* W  = nullptr;   // 300000
    const float* A  = nullptr;   // 19200000
    const float* Bb = nullptr;   // 640000
    const float* px = nullptr;   // 10000
    const void*  p1024[2] = {nullptr, nullptr};
    int n1024 = 0;
    for (int i = 0; i < n_in; i++) {
        switch (in_sizes[i]) {
            case NCELLS * LDIM:        z  = (const float*)d_in[i]; break;
            case LDIM * GDIM:          W  = (const float*)d_in[i]; break;
            case NBATCH * GDIM * LDIM: A  = (const float*)d_in[i]; break;
            case NBATCH * GDIM:        Bb = (const float*)d_in[i]; break;
            case GDIM:                 px = (const float*)d_in[i]; break;
            case NCELLS:
                if (n1024 < 2) p1024[n1024] = d_in[i];
                n1024++;
                break;
            default: break;
        }
    }
    if (!z || !W || !A || !Bb || !px || n1024 != 2) {  // fallback: dict order
        z  = (const float*)d_in[0];
        p1024[0] = d_in[1];
        p1024[1] = d_in[2];
        W  = (const float*)d_in[3];
        A  = (const float*)d_in[4];
        Bb = (const float*)d_in[5];
        px = (const float*)d_in[6];
    }
    float* out = (float*)d_out;

    decoder_kernel<<<dim3(NBATCH, (GDIM + GPB - 1) / GPB), 256, 0, stream>>>(
        z, p1024[0], p1024[1], W, A, Bb, px, out);
}

// Round 7
// 172.635 us; speedup vs baseline: 1.1004x; 1.1004x over previous
//
#include <hip/hip_runtime.h>

#define NCELLS 1024
#define LDIM   30
#define GDIM   10000
#define NBATCH 64
#define GPB    256     // genes per block
#define CH     64      // cell chunk staged in LDS per pass
#define ZSTR   32      // z row stride in LDS (floats): 128 B, float4-aligned

typedef unsigned int u32;

// grid = (NBATCH, ceil(G/GPB)), block = 256, one gene per thread.
// Batch-grouped: fused M[g][l] = W[l,g] + A[b,g,l] built once per (batch,gene),
// reused for all ~16 cells of that batch -> A_emb read from HBM exactly once.
// __launch_bounds__(256,4): LDS (35 KB) already caps us at 4 blocks/CU, so ask
// for exactly 4 waves/EU -> 128-VGPR budget -> M[32] stays in registers
// (R5's VGPR_Count=52 meant M spilled to scratch: the 96 us was L2-latency
// scratch reloads in the inner loop).
__global__ __launch_bounds__(256, 4) void decoder_kernel(
    const float* __restrict__ z,      // [N,L]     f32
    const void*  __restrict__ cand1,  // [N]  bcov or sf (classified on device)
    const void*  __restrict__ cand2,  // [N]  the other one
    const float* __restrict__ W,      // [L,G]     f32
    const float* __restrict__ A,      // [NB,G,L]  f32
    const float* __restrict__ Bb,     // [NB,G]    f32
    const float* __restrict__ px,     // [G]       f32
    float* __restrict__ out)          // [N*G + G] f32
{
    const int b   = blockIdx.x;
    const int tid = threadIdx.x;
    const int gb  = blockIdx.y * GPB;
    const int g   = gb + tid;

    __shared__ __align__(16) float smem[GPB * LDIM];  // A-tile, later z/sf
    __shared__ int cells[NCELLS];
    __shared__ int cnt;

    // classify the two 1024-element inputs: int32 0..63 words all < 64u;
    // uniform-[0,1) f32 bit patterns are not. Uniform address -> scalar loads.
    bool c1_is_int = true;
    for (int i = 0; i < 64; i++)
        if (((const u32*)cand1)[i] >= 64u) { c1_is_int = false; break; }
    const int*   bcov = c1_is_int ? (const int*)cand1   : (const int*)cand2;
    const float* sf   = c1_is_int ? (const float*)cand2 : (const float*)cand1;

    if (tid == 0) cnt = 0;
    __syncthreads();
    for (int i = tid; i < NCELLS; i += 256)
        if (bcov[i] == b) cells[atomicAdd(&cnt, 1)] = i;

    // stage A tile [gb,gb+GPB) x [0,L): coalesced float4 loads (base 16B-aligned)
    const size_t abase = ((size_t)b * GDIM + gb) * LDIM;
    const size_t atot  = (size_t)NBATCH * GDIM * LDIM;
    float4* smem4 = (float4*)smem;
    for (int i = tid; i < GPB * LDIM / 4; i += 256) {
        size_t idx = abase + (size_t)i * 4;
        float4 v = make_float4(0.f, 0.f, 0.f, 0.f);
        if (idx + 4 <= atot) v = *(const float4*)(A + idx);  // b=63 tail clamp
        smem4[i] = v;
    }
    __syncthreads();   // covers cell scan + A staging

    float M[ZSTR];     // fused matrix row, padded to 32 (M[30]=M[31]=0)
    float h3 = 0.f;
    const bool valid = (g < GDIM);
    if (valid) {
        #pragma unroll
        for (int l = 0; l < LDIM; l++) M[l] = smem[tid * LDIM + l] + W[l * GDIM + g];
        M[30] = 0.f; M[31] = 0.f;
        h3 = Bb[(size_t)b * GDIM + g];
        // second output: inverse_dispersion = exp(px_r), f32 at offset N*G
        if (b == 0) out[(size_t)NCELLS * GDIM + g] = __expf(px[g]);
    } else {
        #pragma unroll
        for (int l = 0; l < ZSTR; l++) M[l] = 0.f;
    }
    const int total = cnt;
    __syncthreads();   // A tile fully consumed before smem reuse

    float* z_sh  = smem;               // CH*ZSTR = 2048 floats (8 KB)
    float* sf_sh = smem + CH * ZSTR;   // CH floats
    for (int c0 = 0; c0 < total; c0 += CH) {
        const int nc = min(CH, total - c0);
        for (int i = tid; i < nc * ZSTR; i += 256) {
            int cc = i >> 5, l = i & 31;
            z_sh[i] = (l < LDIM) ? z[(size_t)cells[c0 + cc] * LDIM + l] : 0.f;
        }
        for (int i = tid; i < nc; i += 256)
            sf_sh[i] = sf[cells[c0 + i]];
        __syncthreads();

        if (valid) {
            int cc = 0;
            for (; cc + 2 <= nc; cc += 2) {   // 2 cells, 4 independent FMA chains
                const float4* zr0 = (const float4*)(z_sh + (size_t)cc * ZSTR);
                const float4* zr1 = (const float4*)(z_sh + (size_t)(cc + 1) * ZSTR);
                float a0 = h3, b0 = 0.f, a1 = h3, b1 = 0.f;
                #pragma unroll
                for (int j = 0; j < 8; j++) {
                    float4 p = zr0[j];        // broadcast ds_read_b128
                    float4 q = zr1[j];
                    a0 = fmaf(M[4*j+0], p.x, a0); b0 = fmaf(M[4*j+1], p.y, b0);
                    a0 = fmaf(M[4*j+2], p.z, a0); b0 = fmaf(M[4*j+3], p.w, b0);
                    a1 = fmaf(M[4*j+0], q.x, a1); b1 = fmaf(M[4*j+1], q.y, b1);
                    a1 = fmaf(M[4*j+2], q.z, a1); b1 = fmaf(M[4*j+3], q.w, b1);
                }
                float x0 = a0 + b0, x1 = a1 + b1;
                float s0 = fmaxf(x0, 0.f) + __logf(1.f + __expf(-fabsf(x0)));
                float s1 = fmaxf(x1, 0.f) + __logf(1.f + __expf(-fabsf(x1)));
                out[(size_t)cells[c0 + cc    ] * GDIM + g] = s0 * sf_sh[cc];
                out[(size_t)cells[c0 + cc + 1] * GDIM + g] = s1 * sf_sh[cc + 1];
            }
            if (cc < nc) {                    // odd tail
                const float4* zr0 = (const float4*)(z_sh + (size_t)cc * ZSTR);
                float a0 = h3, b0 = 0.f;
                #pragma unroll
                for (int j = 0; j < 8; j++) {
                    float4 p = zr0[j];
                    a0 = fmaf(M[4*j+0], p.x, a0); b0 = fmaf(M[4*j+1], p.y, b0);
                    a0 = fmaf(M[4*j+2], p.z, a0); b0 = fmaf(M[4*j+3], p.w, b0);
                }
                float x0 = a0 + b0;
                float s0 = fmaxf(x0, 0.f) + __logf(1.f + __expf(-fabsf(x0)));
                out[(size_t)cells[c0 + cc] * GDIM + g] = s0 * sf_sh[cc];
            }
        }
        __syncthreads();
    }
}

extern "C" void kernel_launch(void* const* d_in, const int* in_sizes, int n_in,
                              void* d_out, int out_size, void* d_ws, size_t ws_size,
                              hipStream_t stream) {
    // Bind inputs by element count (robust to ordering); the two 1024-element
    // inputs (bcov / size_factor) are disambiguated on device by content.
    const float* z  = nullptr;   // 30720
    const float* W  = nullptr;   // 300000
    const float* A  = nullptr;   // 19200000
    const float* Bb = nullptr;   // 640000
    const float* px = nullptr;   // 10000
    const void*  p1024[2] = {nullptr, nullptr};
    int n1024 = 0;
    for (int i = 0; i < n_in; i++) {
        switch (in_sizes[i]) {
            case NCELLS * LDIM:        z  = (const float*)d_in[i]; break;
            case LDIM * GDIM:          W  = (const float*)d_in[i]; break;
            case NBATCH * GDIM * LDIM: A  = (const float*)d_in[i]; break;
            case NBATCH * GDIM:        Bb = (const float*)d_in[i]; break;
            case GDIM:                 px = (const float*)d_in[i]; break;
            case NCELLS:
                if (n1024 < 2) p1024[n1024] = d_in[i];
                n1024++;
                break;
            default: break;
        }
    }
    if (!z || !W || !A || !Bb || !px || n1024 != 2) {  // fallback: dict order
        z  = (const float*)d_in[0];
        p1024[0] = d_in[1];
        p1024[1] = d_in[2];
        W  = (const float*)d_in[3];
        A  = (const float*)d_in[4];
        Bb = (const float*)d_in[5];
        px = (const float*)d_in[6];
    }
    float* out = (float*)d_out;

    decoder_kernel<<<dim3(NBATCH, (GDIM + GPB - 1) / GPB), 256, 0, stream>>>(
        z, p1024[0], p1024[1], W, A, Bb, px, out);
}

// Round 8
// 172.564 us; speedup vs baseline: 1.1008x; 1.0004x over previous
//
#include <hip/hip_runtime.h>

#define NCELLS 1024
#define LDIM   30
#define GDIM   10000
#define NBATCH 64
#define GPB    256     // genes per block

typedef unsigned int u32;

// grid = (NBATCH, ceil(G/GPB)), block = 256, one gene per thread.
// Batch-grouped: fused M[g][l] = W[l,g] + A[b,g,l] built once per (batch,gene),
// reused for all ~16 cells of the batch -> A_emb read from HBM exactly once.
// z rows are WAVE-UNIFORM per cell: cell index goes through readfirstlane so
// z/sf loads compile to scalar (SMEM) loads and FMAs take the SGPR operand —
// no LDS traffic in the cell loop at all (R7 was LDS-issue-bound: 128
// ds_read_b128/thread ~= 26 us of LDS pipe).
__global__ __launch_bounds__(256, 4) void decoder_kernel(
    const float* __restrict__ z,      // [N,L]     f32
    const void*  __restrict__ cand1,  // [N]  bcov or sf (classified on device)
    const void*  __restrict__ cand2,  // [N]  the other one
    const float* __restrict__ W,      // [L,G]     f32
    const float* __restrict__ A,      // [NB,G,L]  f32
    const float* __restrict__ Bb,     // [NB,G]    f32
    const float* __restrict__ px,     // [G]       f32
    float* __restrict__ out)          // [N*G + G] f32
{
    const int b   = blockIdx.x;
    const int tid = threadIdx.x;
    const int gb  = blockIdx.y * GPB;
    const int g   = gb + tid;

    __shared__ __align__(16) float a_sh[GPB * LDIM];  // 30 KB A-tile
    __shared__ int cells[NCELLS];
    __shared__ int cnt;

    // classify the two 1024-element inputs: int32 0..63 words all < 64u;
    // uniform-[0,1) f32 bit patterns are not. Uniform branch, L2-hot.
    bool c1_is_int = true;
    for (int i = 0; i < 64; i++)
        if (((const u32*)cand1)[i] >= 64u) { c1_is_int = false; break; }
    const int*   bcov = c1_is_int ? (const int*)cand1   : (const int*)cand2;
    const float* sf   = c1_is_int ? (const float*)cand2 : (const float*)cand1;

    if (tid == 0) cnt = 0;
    __syncthreads();
    for (int i = tid; i < NCELLS; i += 256)
        if (bcov[i] == b) cells[atomicAdd(&cnt, 1)] = i;

    // stage A tile [gb,gb+GPB) x [0,L): coalesced float4 (base 16B-aligned)
    const size_t abase = ((size_t)b * GDIM + gb) * LDIM;
    const size_t atot  = (size_t)NBATCH * GDIM * LDIM;
    float4* a4 = (float4*)a_sh;
    for (int i = tid; i < GPB * LDIM / 4; i += 256) {
        size_t idx = abase + (size_t)i * 4;
        float4 v = make_float4(0.f, 0.f, 0.f, 0.f);
        if (idx + 4 <= atot) v = *(const float4*)(A + idx);  // b=63 tail clamp
        a4[i] = v;
    }
    __syncthreads();   // covers cell scan + A staging; LAST barrier in kernel

    const int total = cnt;
    if (g >= GDIM) return;            // safe: no __syncthreads below

    // fused matrix row in registers: M[l] = a_sh[tid][l] + W[l,g]
    // a_sh + tid*30 is 8B-aligned (120 B/row) -> ds_read_b64 pairs
    float M[LDIM];
    {
        const float2* ar = (const float2*)(a_sh + tid * LDIM);
        #pragma unroll
        for (int j = 0; j < LDIM / 2; j++) {
            float2 w = ar[j];
            M[2*j]   = w.x + W[(2*j)   * GDIM + g];   // W coalesced, L2/L3-hot
            M[2*j+1] = w.y + W[(2*j+1) * GDIM + g];
        }
    }
    const float h3 = Bb[(size_t)b * GDIM + g];
    // second output: inverse_dispersion = exp(px_r), f32 at offset N*G
    if (b == 0) out[(size_t)NCELLS * GDIM + g] = __expf(px[g]);

    int c = 0;
    for (; c + 2 <= total; c += 2) {   // 2 cells x 2 chains = 4 indep FMA chains
        const int cell0 = __builtin_amdgcn_readfirstlane(cells[c]);
        const int cell1 = __builtin_amdgcn_readfirstlane(cells[c + 1]);
        const float* z0 = z + (size_t)cell0 * LDIM;   // uniform -> s_load
        const float* z1 = z + (size_t)cell1 * LDIM;
        const float s0 = sf[cell0], s1 = sf[cell1];   // uniform -> s_load
        float a0 = h3, b0 = 0.f, a1 = h3, b1 = 0.f;
        #pragma unroll
        for (int l = 0; l < LDIM; l += 2) {
            a0 = fmaf(M[l],     z0[l],     a0);
            b0 = fmaf(M[l + 1], z0[l + 1], b0);
            a1 = fmaf(M[l],     z1[l],     a1);
            b1 = fmaf(M[l + 1], z1[l + 1], b1);
        }
        float x0 = a0 + b0, x1 = a1 + b1;
        // stable softplus: max(x,0) + log(1 + exp(-|x|))
        float p0 = fmaxf(x0, 0.f) + __logf(1.f + __expf(-fabsf(x0)));
        float p1 = fmaxf(x1, 0.f) + __logf(1.f + __expf(-fabsf(x1)));
        out[(size_t)cell0 * GDIM + g] = p0 * s0;      // lanes consecutive g
        out[(size_t)cell1 * GDIM + g] = p1 * s1;
    }
    if (c < total) {                   // odd tail
        const int cell0 = __builtin_amdgcn_readfirstlane(cells[c]);
        const float* z0 = z + (size_t)cell0 * LDIM;
        const float s0 = sf[cell0];
        float a0 = h3, b0 = 0.f;
        #pragma unroll
        for (int l = 0; l < LDIM; l += 2) {
            a0 = fmaf(M[l],     z0[l],     a0);
            b0 = fmaf(M[l + 1], z0[l + 1], b0);
        }
        float x0 = a0 + b0;
        float p0 = fmaxf(x0, 0.f) + __logf(1.f + __expf(-fabsf(x0)));
        out[(size_t)cell0 * GDIM + g] = p0 * s0;
    }
}

extern "C" void kernel_launch(void* const* d_in, const int* in_sizes, int n_in,
                              void* d_out, int out_size, void* d_ws, size_t ws_size,
                              hipStream_t stream) {
    // Bind inputs by element count (robust to ordering); the two 1024-element
    // inputs (bcov / size_factor) are disambiguated on device by content.
    const float* z  = nullptr;   // 30720
    const float* W  = nullptr;   // 300000
    const float* A  = nullptr;   // 19200000
    const float* Bb = nullptr;   // 640000
    const float* px = nullptr;   // 10000
    const void*  p1024[2] = {nullptr, nullptr};
    int n1024 = 0;
    for (int i = 0; i < n_in; i++) {
        switch (in_sizes[i]) {
            case NCELLS * LDIM:        z  = (const float*)d_in[i]; break;
            case LDIM * GDIM:          W  = (const float*)d_in[i]; break;
            case NBATCH * GDIM * LDIM: A  = (const float*)d_in[i]; break;
            case NBATCH * GDIM:        Bb = (const float*)d_in[i]; break;
            case GDIM:                 px = (const float*)d_in[i]; break;
            case NCELLS:
                if (n1024 < 2) p1024[n1024] = d_in[i];
                n1024++;
                break;
            default: break;
        }
    }
    if (!z || !W || !A || !Bb || !px || n1024 != 2) {  // fallback: dict order
        z  = (const float*)d_in[0];
        p1024[0] = d_in[1];
        p1024[1] = d_in[2];
        W  = (const float*)d_in[3];
        A  = (const float*)d_in[4];
        Bb = (const float*)d_in[5];
        px = (const float*)d_in[6];
    }
    float* out = (float*)d_out;

    decoder_kernel<<<dim3(NBATCH, (GDIM + GPB - 1) / GPB), 256, 0, stream>>>(
        z, p1024[0], p1024[1], W, A, Bb, px, out);
}